// Round 4
// baseline (693.529 us; speedup 1.0000x reference)
//
#include <hip/hip_runtime.h>
#include <hip/hip_fp16.h>

#define RES 512
#define FEAT 32
#define NPLANES 6
#define TPH (RES + 8)   // fp16 LDS row pitch (halves): 520 -> odd word stride, <=2-way banks

typedef float f4 __attribute__((ext_vector_type(4)));

// ---------------------------------------------------------------------------
// Transpose + downconvert: [p][c][y][x] fp32 -> [p][y][x][c] fp16.
// Byte-identical to Round 3 (diagnostic round: sampler is split in two so
// this kernel surfaces in rocprof top-5 with full counters).
// ---------------------------------------------------------------------------
__global__ __launch_bounds__(256) void transpose_fp16_kernel(
    const float* __restrict__ in, __half* __restrict__ out)
{
    __shared__ __half tile[FEAT][TPH];
    const int b = blockIdx.x;
    const int y = b & (RES - 1);
    const int p = b >> 9;               // 512 blocks per plane

    const size_t pb = (size_t)p * ((size_t)FEAT * RES * RES) + (size_t)y * RES;
    #pragma unroll
    for (int j = 0; j < 16; ++j) {
        const int f  = threadIdx.x + j * 256;   // float4 index 0..4095
        const int c  = f >> 7;                  // 128 float4 per 512-wide row
        const int x4 = (f & 127) << 2;
        const f4 v = __builtin_nontemporal_load(
            (const f4*)(in + pb + (size_t)c * (RES * RES) + x4));
        union { __half h[4]; float2 f2; } u;
        u.h[0] = __float2half_rn(v[0]);
        u.h[1] = __float2half_rn(v[1]);
        u.h[2] = __float2half_rn(v[2]);
        u.h[3] = __float2half_rn(v[3]);
        *(float2*)&tile[c][x4] = u.f2;          // 8 B LDS write, minimal banking
    }
    __syncthreads();

    // Phase 2: thread t covers x = (t>>1) + 128*it, channels c0..c0+15.
    const int xl = threadIdx.x >> 1;
    const int c0 = (threadIdx.x & 1) << 4;
    const size_t ob0 = ((size_t)(p * RES + y) * RES) * FEAT + c0;
    #pragma unroll
    for (int it = 0; it < 4; ++it) {
        const int x = xl + (it << 7);
        union { __half h[16]; float4 q[2]; } u;
        #pragma unroll
        for (int j = 0; j < 16; ++j)
            u.h[j] = tile[c0 + j][x];
        __half* o = out + ob0 + (size_t)x * FEAT;
        *(float4*)o       = u.q[0];
        *(float4*)(o + 8) = u.q[1];
    }
}

// ---------------------------------------------------------------------------
// Sampler: 4 threads per point, 8 channels per thread. Handles points in
// [p0, p1) so the launch can be split into two dispatches (profiling
// attribution); algorithm identical to Round 3.
// ---------------------------------------------------------------------------
__device__ __forceinline__ void unpack8(const float4 r, float* o)
{
    const __half2* h = (const __half2*)&r;
    float2 p;
    p = __half22float2(h[0]); o[0] = p.x; o[1] = p.y;
    p = __half22float2(h[1]); o[2] = p.x; o[3] = p.y;
    p = __half22float2(h[2]); o[4] = p.x; o[5] = p.y;
    p = __half22float2(h[3]); o[6] = p.x; o[7] = p.y;
}

__global__ __launch_bounds__(256) void sample_fp16_kernel(
    const float* __restrict__ pts, const float* __restrict__ tm,
    const __half* __restrict__ planes, float* __restrict__ out,
    int npts, int p0, int p1)
{
    const int t  = blockIdx.x * 256 + threadIdx.x;
    const int pt = p0 + (t >> 2);
    const int sub = t & 3;
    if (pt >= p1) return;

    float d[4];
    d[0] = (pts[(size_t)pt * 3 + 0] + 1.6f) / 3.2f * 2.0f - 1.0f;
    d[1] = (pts[(size_t)pt * 3 + 1] + 1.6f) / 3.2f * 2.0f - 1.0f;
    d[2] = (pts[(size_t)pt * 3 + 2] + 1.6f) / 3.2f * 2.0f - 1.0f;
    d[3] = tm[pt] * 2.0f - 1.0f;

    const int xi[NPLANES] = {0, 0, 3, 1, 3, 3};
    const int yi[NPLANES] = {1, 2, 0, 2, 1, 2};

    // Phase A: all addresses + weights (pure VALU, no memory).
    int   off[NPLANES][4];
    float w[NPLANES][4];
    #pragma unroll
    for (int q = 0; q < NPLANES; ++q) {
        const float u = d[xi[q]];
        const float v = d[yi[q]];
        float fx = fminf(fmaxf((u + 1.0f) * 0.5f * 511.0f, 0.0f), 511.0f);
        float fy = fminf(fmaxf((v + 1.0f) * 0.5f * 511.0f, 0.0f), 511.0f);
        const float x0f = floorf(fx), y0f = floorf(fy);
        const float wx = fx - x0f,   wy = fy - y0f;
        const int x0 = (int)x0f, y0 = (int)y0f;
        const int x1 = min(x0 + 1, RES - 1), y1 = min(y0 + 1, RES - 1);
        const int r0 = y0 << 9, r1 = y1 << 9;
        off[q][0] = (r0 + x0) << 5;
        off[q][1] = (r0 + x1) << 5;
        off[q][2] = (r1 + x0) << 5;
        off[q][3] = (r1 + x1) << 5;
        w[q][0] = (1.0f - wx) * (1.0f - wy);
        w[q][1] = wx * (1.0f - wy);
        w[q][2] = (1.0f - wx) * wy;
        w[q][3] = wx * wy;
    }

    // Phase B: issue all 24 tap loads back-to-back.
    float4 a[NPLANES][4];
    #pragma unroll
    for (int q = 0; q < NPLANES; ++q) {
        const __half* P = planes + ((size_t)q << 23) + (sub << 3);
        #pragma unroll
        for (int k = 0; k < 4; ++k)
            a[q][k] = *(const float4*)(P + off[q][k]);
    }

    // Phase C: per-plane bilinear combine.
    float fq[NPLANES][8];
    #pragma unroll
    for (int q = 0; q < NPLANES; ++q) {
        float v00[8], v01[8], v10[8], v11[8];
        unpack8(a[q][0], v00); unpack8(a[q][1], v01);
        unpack8(a[q][2], v10); unpack8(a[q][3], v11);
        #pragma unroll
        for (int i = 0; i < 8; ++i)
            fq[q][i] = v00[i] * w[q][0] + v01[i] * w[q][1]
                     + v10[i] * w[q][2] + v11[i] * w[q][3];
    }

    {
        float sp[8], st[8];
        #pragma unroll
        for (int i = 0; i < 8; ++i) {
            sp[i] = fq[0][i] * fq[1][i] * fq[3][i];
            st[i] = fq[2][i] * fq[4][i] * fq[5][i];
        }
        float4* o = (float4*)(out + (size_t)pt * FEAT + (sub << 3));
        o[0] = *(float4*)&sp[0];
        o[1] = *(float4*)&sp[4];
        float4* o2 = (float4*)(out + (size_t)npts * FEAT + (size_t)pt * FEAT + (sub << 3));
        o2[0] = *(float4*)&st[0];
        o2[1] = *(float4*)&st[4];
    }
}

// ---------------------------------------------------------------------------
// Fallback (ws too small): sample original [p][c][y][x] fp32 layout directly.
// ---------------------------------------------------------------------------
__global__ __launch_bounds__(256) void sample_fallback_kernel(
    const float* __restrict__ pts, const float* __restrict__ tm,
    const float* __restrict__ planes, float* __restrict__ out, int npts)
{
    const int t  = blockIdx.x * 256 + threadIdx.x;
    const int pt = t >> 5;
    const int c  = t & 31;
    if (pt >= npts) return;

    float d[4];
    d[0] = (pts[(size_t)pt * 3 + 0] + 1.6f) / 3.2f * 2.0f - 1.0f;
    d[1] = (pts[(size_t)pt * 3 + 1] + 1.6f) / 3.2f * 2.0f - 1.0f;
    d[2] = (pts[(size_t)pt * 3 + 2] + 1.6f) / 3.2f * 2.0f - 1.0f;
    d[3] = tm[pt] * 2.0f - 1.0f;

    const int xi[NPLANES] = {0, 0, 3, 1, 3, 3};
    const int yi[NPLANES] = {1, 2, 0, 2, 1, 2};
    float f[NPLANES];
    #pragma unroll
    for (int q = 0; q < NPLANES; ++q) {
        const float u = d[xi[q]], v = d[yi[q]];
        float fx = fminf(fmaxf((u + 1.0f) * 0.5f * 511.0f, 0.0f), 511.0f);
        float fy = fminf(fmaxf((v + 1.0f) * 0.5f * 511.0f, 0.0f), 511.0f);
        const float x0f = floorf(fx), y0f = floorf(fy);
        const float wx = fx - x0f, wy = fy - y0f;
        const int x0 = (int)x0f, y0 = (int)y0f;
        const int x1 = min(x0 + 1, RES - 1), y1 = min(y0 + 1, RES - 1);
        const float* P = planes + ((size_t)(q * FEAT + c) << 18);
        const int r0 = y0 << 9, r1 = y1 << 9;
        f[q] = P[r0 + x0] * ((1.0f - wx) * (1.0f - wy)) + P[r0 + x1] * (wx * (1.0f - wy)) +
               P[r1 + x0] * ((1.0f - wx) * wy)          + P[r1 + x1] * (wx * wy);
    }
    out[(size_t)pt * FEAT + c] = f[0] * f[1] * f[3];
    out[(size_t)npts * FEAT + (size_t)pt * FEAT + c] = f[2] * f[4] * f[5];
}

extern "C" void kernel_launch(void* const* d_in, const int* in_sizes, int n_in,
                              void* d_out, int out_size, void* d_ws, size_t ws_size,
                              hipStream_t stream) {
    const float* pts    = (const float*)d_in[0];
    const float* tm     = (const float*)d_in[1];
    const float* planes = (const float*)d_in[2];
    float* out = (float*)d_out;
    const int npts = in_sizes[0] / 3;

    const size_t need = (size_t)NPLANES * FEAT * RES * RES * sizeof(__half);  // 96 MiB
    if (ws_size >= need) {
        __half* T = (__half*)d_ws;
        transpose_fp16_kernel<<<NPLANES * RES, 256, 0, stream>>>(planes, T);
        const int half = npts / 2;
        {
            const int blocks = (half * 4 + 255) / 256;
            sample_fp16_kernel<<<blocks, 256, 0, stream>>>(pts, tm, T, out, npts, 0, half);
        }
        {
            const int n2 = npts - half;
            const int blocks = (n2 * 4 + 255) / 256;
            sample_fp16_kernel<<<blocks, 256, 0, stream>>>(pts, tm, T, out, npts, half, npts);
        }
    } else {
        const int blocks = (npts * 32 + 255) / 256;
        sample_fallback_kernel<<<blocks, 256, 0, stream>>>(pts, tm, planes, out, npts);
    }
}

// Round 5
// 691.833 us; speedup vs baseline: 1.0025x; 1.0025x over previous
//
#include <hip/hip_runtime.h>
#include <hip/hip_fp16.h>

#define RES 512
#define FEAT 32
#define NPLANES 6
#define TPH (256 + 8)   // fp16 LDS row pitch (halves) for 256-wide half-row tiles

typedef float f4 __attribute__((ext_vector_type(4)));

// ---------------------------------------------------------------------------
// Transpose + downconvert: [p][c][y][x] fp32 -> [p][y][x][c] fp16.
// v3: block = (plane, row, half-row of 256). LDS 16.9 KB -> 8 blocks/CU
// (was 4 at 33 KB), doubling resident read streams. Reads 1 KB contiguous
// per wave-load, writes 16 KB contiguous per block.
// ---------------------------------------------------------------------------
__global__ __launch_bounds__(256) void transpose_fp16_kernel(
    const float* __restrict__ in, __half* __restrict__ out)
{
    __shared__ __half tile[FEAT][TPH];
    const int b  = blockIdx.x;
    const int xh = b & 1;               // half-row
    const int y  = (b >> 1) & (RES - 1);
    const int p  = b >> 10;             // 1024 blocks per plane
    const int xbase = xh << 8;

    const size_t pb = (size_t)p * ((size_t)FEAT * RES * RES) + (size_t)y * RES + xbase;
    #pragma unroll
    for (int j = 0; j < 8; ++j) {
        const int f  = threadIdx.x + j * 256;   // float4 index 0..2047
        const int c  = f >> 6;                  // 64 float4 per 256-wide half-row
        const int x4 = (f & 63) << 2;
        const f4 v = __builtin_nontemporal_load(
            (const f4*)(in + pb + (size_t)c * (RES * RES) + x4));
        union { __half h[4]; float2 f2; } u;
        u.h[0] = __float2half_rn(v[0]);
        u.h[1] = __float2half_rn(v[1]);
        u.h[2] = __float2half_rn(v[2]);
        u.h[3] = __float2half_rn(v[3]);
        *(float2*)&tile[c][x4] = u.f2;          // 8 B LDS write
    }
    __syncthreads();

    // Thread t covers x = (t>>1) + 128*it (it<2), channels c0..c0+15.
    const int xl = threadIdx.x >> 1;
    const int c0 = (threadIdx.x & 1) << 4;
    const size_t ob0 = (((size_t)(p * RES + y) * RES) + xbase) * FEAT + c0;
    #pragma unroll
    for (int it = 0; it < 2; ++it) {
        const int x = xl + (it << 7);
        union { __half h[16]; float4 q[2]; } u;
        #pragma unroll
        for (int j = 0; j < 16; ++j)
            u.h[j] = tile[c0 + j][x];
        __half* o = out + ob0 + (size_t)x * FEAT;
        *(float4*)o       = u.q[0];
        *(float4*)(o + 8) = u.q[1];
    }
}

// ---------------------------------------------------------------------------
// Sampler: 4 threads per point, 8 channels per thread.
// v3: __launch_bounds__(256, 2) lifts the 64-VGPR cap that silently
// serialized Phase B (24 float4 dests = 96 VGPR don't fit in 64 -> compiler
// batched loads ~8-deep with waitcnts; rocprof showed VGPR_Count=64).
// Now all 24 tap lines can be in flight per wave: 12 waves/CU x 24 lines
// vs x ~8 before.
// ---------------------------------------------------------------------------
__device__ __forceinline__ void unpack8(const float4 r, float* o)
{
    const __half2* h = (const __half2*)&r;
    float2 p;
    p = __half22float2(h[0]); o[0] = p.x; o[1] = p.y;
    p = __half22float2(h[1]); o[2] = p.x; o[3] = p.y;
    p = __half22float2(h[2]); o[4] = p.x; o[5] = p.y;
    p = __half22float2(h[3]); o[6] = p.x; o[7] = p.y;
}

__global__ __launch_bounds__(256, 2) void sample_fp16_kernel(
    const float* __restrict__ pts, const float* __restrict__ tm,
    const __half* __restrict__ planes, float* __restrict__ out, int npts)
{
    const int t  = blockIdx.x * 256 + threadIdx.x;
    const int pt = t >> 2;
    const int sub = t & 3;
    if (pt >= npts) return;

    float d[4];
    d[0] = (pts[(size_t)pt * 3 + 0] + 1.6f) / 3.2f * 2.0f - 1.0f;
    d[1] = (pts[(size_t)pt * 3 + 1] + 1.6f) / 3.2f * 2.0f - 1.0f;
    d[2] = (pts[(size_t)pt * 3 + 2] + 1.6f) / 3.2f * 2.0f - 1.0f;
    d[3] = tm[pt] * 2.0f - 1.0f;

    const int xi[NPLANES] = {0, 0, 3, 1, 3, 3};
    const int yi[NPLANES] = {1, 2, 0, 2, 1, 2};

    // Phase A: all 6 planes' addresses + weights (pure VALU).
    int   off[NPLANES][4];
    float w[NPLANES][4];
    #pragma unroll
    for (int q = 0; q < NPLANES; ++q) {
        const float u = d[xi[q]];
        const float v = d[yi[q]];
        float fx = fminf(fmaxf((u + 1.0f) * 0.5f * 511.0f, 0.0f), 511.0f);
        float fy = fminf(fmaxf((v + 1.0f) * 0.5f * 511.0f, 0.0f), 511.0f);
        const float x0f = floorf(fx), y0f = floorf(fy);
        const float wx = fx - x0f,   wy = fy - y0f;
        const int x0 = (int)x0f, y0 = (int)y0f;
        const int x1 = min(x0 + 1, RES - 1), y1 = min(y0 + 1, RES - 1);
        const int r0 = y0 << 9, r1 = y1 << 9;
        off[q][0] = (r0 + x0) << 5;
        off[q][1] = (r0 + x1) << 5;
        off[q][2] = (r1 + x0) << 5;
        off[q][3] = (r1 + x1) << 5;
        w[q][0] = (1.0f - wx) * (1.0f - wy);
        w[q][1] = wx * (1.0f - wy);
        w[q][2] = (1.0f - wx) * wy;
        w[q][3] = wx * wy;
    }

    // Phase B: issue all 24 tap loads back-to-back (96 VGPR of dests).
    float4 a[NPLANES][4];
    #pragma unroll
    for (int q = 0; q < NPLANES; ++q) {
        const __half* P = planes + ((size_t)q << 23) + (sub << 3);
        #pragma unroll
        for (int k = 0; k < 4; ++k)
            a[q][k] = *(const float4*)(P + off[q][k]);
    }

    // Phase C: per-plane bilinear combine.
    float fq[NPLANES][8];
    #pragma unroll
    for (int q = 0; q < NPLANES; ++q) {
        float v00[8], v01[8], v10[8], v11[8];
        unpack8(a[q][0], v00); unpack8(a[q][1], v01);
        unpack8(a[q][2], v10); unpack8(a[q][3], v11);
        #pragma unroll
        for (int i = 0; i < 8; ++i)
            fq[q][i] = v00[i] * w[q][0] + v01[i] * w[q][1]
                     + v10[i] * w[q][2] + v11[i] * w[q][3];
    }

    {
        float sp[8], st[8];
        #pragma unroll
        for (int i = 0; i < 8; ++i) {
            sp[i] = fq[0][i] * fq[1][i] * fq[3][i];
            st[i] = fq[2][i] * fq[4][i] * fq[5][i];
        }
        float4* o = (float4*)(out + (size_t)pt * FEAT + (sub << 3));
        o[0] = *(float4*)&sp[0];
        o[1] = *(float4*)&sp[4];
        float4* o2 = (float4*)(out + (size_t)npts * FEAT + (size_t)pt * FEAT + (sub << 3));
        o2[0] = *(float4*)&st[0];
        o2[1] = *(float4*)&st[4];
    }
}

// ---------------------------------------------------------------------------
// Fallback (ws too small): sample original [p][c][y][x] fp32 layout directly.
// ---------------------------------------------------------------------------
__global__ __launch_bounds__(256) void sample_fallback_kernel(
    const float* __restrict__ pts, const float* __restrict__ tm,
    const float* __restrict__ planes, float* __restrict__ out, int npts)
{
    const int t  = blockIdx.x * 256 + threadIdx.x;
    const int pt = t >> 5;
    const int c  = t & 31;
    if (pt >= npts) return;

    float d[4];
    d[0] = (pts[(size_t)pt * 3 + 0] + 1.6f) / 3.2f * 2.0f - 1.0f;
    d[1] = (pts[(size_t)pt * 3 + 1] + 1.6f) / 3.2f * 2.0f - 1.0f;
    d[2] = (pts[(size_t)pt * 3 + 2] + 1.6f) / 3.2f * 2.0f - 1.0f;
    d[3] = tm[pt] * 2.0f - 1.0f;

    const int xi[NPLANES] = {0, 0, 3, 1, 3, 3};
    const int yi[NPLANES] = {1, 2, 0, 2, 1, 2};
    float f[NPLANES];
    #pragma unroll
    for (int q = 0; q < NPLANES; ++q) {
        const float u = d[xi[q]], v = d[yi[q]];
        float fx = fminf(fmaxf((u + 1.0f) * 0.5f * 511.0f, 0.0f), 511.0f);
        float fy = fminf(fmaxf((v + 1.0f) * 0.5f * 511.0f, 0.0f), 511.0f);
        const float x0f = floorf(fx), y0f = floorf(fy);
        const float wx = fx - x0f, wy = fy - y0f;
        const int x0 = (int)x0f, y0 = (int)y0f;
        const int x1 = min(x0 + 1, RES - 1), y1 = min(y0 + 1, RES - 1);
        const float* P = planes + ((size_t)(q * FEAT + c) << 18);
        const int r0 = y0 << 9, r1 = y1 << 9;
        f[q] = P[r0 + x0] * ((1.0f - wx) * (1.0f - wy)) + P[r0 + x1] * (wx * (1.0f - wy)) +
               P[r1 + x0] * ((1.0f - wx) * wy)          + P[r1 + x1] * (wx * wy);
    }
    out[(size_t)pt * FEAT + c] = f[0] * f[1] * f[3];
    out[(size_t)npts * FEAT + (size_t)pt * FEAT + c] = f[2] * f[4] * f[5];
}

extern "C" void kernel_launch(void* const* d_in, const int* in_sizes, int n_in,
                              void* d_out, int out_size, void* d_ws, size_t ws_size,
                              hipStream_t stream) {
    const float* pts    = (const float*)d_in[0];
    const float* tm     = (const float*)d_in[1];
    const float* planes = (const float*)d_in[2];
    float* out = (float*)d_out;
    const int npts = in_sizes[0] / 3;

    const size_t need = (size_t)NPLANES * FEAT * RES * RES * sizeof(__half);  // 96 MiB
    if (ws_size >= need) {
        __half* T = (__half*)d_ws;
        transpose_fp16_kernel<<<NPLANES * RES * 2, 256, 0, stream>>>(planes, T);
        const int blocks = (npts * 4 + 255) / 256;
        sample_fp16_kernel<<<blocks, 256, 0, stream>>>(pts, tm, T, out, npts);
    } else {
        const int blocks = (npts * 32 + 255) / 256;
        sample_fallback_kernel<<<blocks, 256, 0, stream>>>(pts, tm, planes, out, npts);
    }
}